// Round 3
// baseline (7616.737 us; speedup 1.0000x reference)
//
#include <hip/hip_runtime.h>
#include <hip/hip_bf16.h>

#define N_NODES 100000
#define N_EDGES 1600000

// A 200-column fp32 matrix stored as two 100-col panels (p0: cols 0-99,
// p1: cols 100-199). Contiguous [M,200] is View{base, base+100, 200};
// split panels are View{q0, q1, 100}. Lets us borrow d_out (exactly
// 100000*100 floats) as the second panel when ws_size is small.
struct View {
    float* p0;
    float* p1;
    int stride;
};

__device__ __forceinline__ float* vaddr(const View v, int row, int col) {
    return (col < 100) ? (v.p0 + (size_t)row * v.stride + col)
                       : (v.p1 + (size_t)row * v.stride + (col - 100));
}

// ---------------- GEMM: C = op(A[M,K]) @ W[K,N] (+bias,+relu if FINAL) ----
template <bool RELU_IN, bool FINAL>
__global__ __launch_bounds__(256)
void gemm_k(const float* __restrict__ A, const float* __restrict__ W,
            const float* __restrict__ bias, View C, int M, int N, int K) {
    constexpr int TS = 64;
    constexpr int KS = 16;
    __shared__ float As[KS][TS + 1];
    __shared__ float Bs[KS][TS + 1];

    const int tid = threadIdx.x;
    const int tx = tid & 15;
    const int ty = tid >> 4;
    const int row0 = blockIdx.y * TS;
    const int col0 = blockIdx.x * TS;

    float acc[4][4] = {};

    for (int k0 = 0; k0 < K; k0 += KS) {
        #pragma unroll
        for (int l = 0; l < 4; ++l) {
            int e = tid + l * 256;
            int ar = e >> 4;
            int ac = e & 15;
            int gr = row0 + ar, gc = k0 + ac;
            float v = 0.f;
            if (gr < M && gc < K) v = A[(size_t)gr * K + gc];
            if (RELU_IN) v = fmaxf(v, 0.f);
            As[ac][ar] = v;
        }
        #pragma unroll
        for (int l = 0; l < 4; ++l) {
            int e = tid + l * 256;
            int br = e >> 6;
            int bc = e & 63;
            int gr = k0 + br, gc = col0 + bc;
            float v = 0.f;
            if (gr < K && gc < N) v = W[(size_t)gr * N + gc];
            Bs[br][bc] = v;
        }
        __syncthreads();

        #pragma unroll
        for (int kk = 0; kk < KS; ++kk) {
            float a[4], b[4];
            #pragma unroll
            for (int i = 0; i < 4; ++i) a[i] = As[kk][ty * 4 + i];
            #pragma unroll
            for (int j = 0; j < 4; ++j) b[j] = Bs[kk][tx * 4 + j];
            #pragma unroll
            for (int i = 0; i < 4; ++i)
                #pragma unroll
                for (int j = 0; j < 4; ++j)
                    acc[i][j] += a[i] * b[j];
        }
        __syncthreads();
    }

    #pragma unroll
    for (int i = 0; i < 4; ++i) {
        int gr = row0 + ty * 4 + i;
        if (gr >= M) continue;
        #pragma unroll
        for (int j = 0; j < 4; ++j) {
            int gc = col0 + tx * 4 + j;
            if (gc >= N) continue;
            float v = acc[i][j];
            if (FINAL) v = fmaxf(v + bias[gc], 0.f);
            *vaddr(C, gr, gc) = v;
        }
    }
}

// ---------------- Scatter: dst[didx[e], f] += w[e] * op(src[sidx[e], f]) ---
// One thread per (edge, feature) pair; f = idx % 200 keeps loads coalesced.
template <bool RELU_SRC>
__global__ __launch_bounds__(256)
void scatter_k(View src, View dst, const int* __restrict__ sidx,
               const int* __restrict__ didx, const float* __restrict__ w,
               int E) {
    int idx = blockIdx.x * 256 + threadIdx.x;
    int e = idx / 200;
    int f = idx - e * 200;
    if (e >= E) return;
    int s = sidx[e];
    int d = didx[e];
    float val = *vaddr(src, s, f);
    if (RELU_SRC) val = fmaxf(val, 0.f);
    atomicAdd(vaddr(dst, d, f), w[e] * val);
}

// ---------------- Fused: Out = relu(A[M,200] @ W2[200,300]) @ W3[300,200] --
// Row-tile of 64; t (=h2 rows) lives in LDS tiled over k2 in steps of 48,
// so no [M,300] intermediate is ever materialized. 64000 B static LDS.
__global__ __launch_bounds__(256)
void fused_gemm_k(const float* __restrict__ A, const float* __restrict__ W2,
                  const float* __restrict__ W3, View Out, int M) {
    __shared__ float A_s[64 * 201];   // padded: stride 201 -> conflict-free
    __shared__ float t_s[64 * 49];    // 48-wide k2 tile, padded to 49

    const int tid = threadIdx.x;
    const int r = tid & 63;           // row within tile (one lane per row)
    const int wv = tid >> 6;          // wave id 0..3
    const int row0 = blockIdx.x * 64;

    for (int e = tid; e < 64 * 200; e += 256) {
        int rr = e / 200;
        int cc = e - rr * 200;
        int gr = row0 + rr;
        A_s[rr * 201 + cc] = (gr < M) ? A[(size_t)gr * 200 + cc] : 0.f;
    }
    __syncthreads();

    const int c0 = wv * 50;           // this thread's 50 output columns
    float acc[50];
    #pragma unroll
    for (int j = 0; j < 50; ++j) acc[j] = 0.f;

    for (int kb = 0; kb < 300; kb += 48) {
        const int TB = (300 - kb) < 48 ? (300 - kb) : 48;  // 48,...,48,12
        // phase 1: t_s[r][cl] = relu(sum_k A_s[r][k] * W2[k][kb+cl])
        for (int cl = wv; cl < TB; cl += 4) {
            float s = 0.f;
            #pragma unroll 4
            for (int k = 0; k < 200; ++k)
                s += A_s[r * 201 + k] * W2[(size_t)k * 300 + (kb + cl)];
            t_s[r * 49 + cl] = fmaxf(s, 0.f);
        }
        __syncthreads();
        // phase 2: acc[j] += t_s[r][cl] * W3[kb+cl][c0+j]
        for (int cl = 0; cl < TB; ++cl) {
            float tv = t_s[r * 49 + cl];
            const float* w3row = W3 + (size_t)(kb + cl) * 200 + c0;
            #pragma unroll
            for (int j = 0; j < 50; ++j)
                acc[j] += tv * w3row[j];
        }
        __syncthreads();
    }

    int gr = row0 + r;
    if (gr < M) {
        #pragma unroll
        for (int j = 0; j < 50; ++j)
            *vaddr(Out, gr, c0 + j) = acc[j];
    }
}

extern "C" void kernel_launch(void* const* d_in, const int* in_sizes, int n_in,
                              void* d_out, int out_size, void* d_ws, size_t ws_size,
                              hipStream_t stream) {
    const float* feat_x = (const float*)d_in[0];
    const int*   src    = (const int*)d_in[1];
    const int*   dst    = (const int*)d_in[2];
    const float* ew     = (const float*)d_in[3];
    const float* W1     = (const float*)d_in[4];
    const float* W2     = (const float*)d_in[5];
    const float* W3     = (const float*)d_in[6];
    const float* W_out  = (const float*)d_in[7];
    const float* b_out  = (const float*)d_in[8];
    float* out = (float*)d_out;

    // Workspace budget: P = [M,200] contiguous (80 MB), Q = two [M,100]
    // panels. q1 borrows d_out (dead until the final GEMM) unless ws_size
    // can hold it too. Total d_ws use: 120 MB (or 160 MB).
    const size_t PE = (size_t)N_NODES * 200;   // 20,000,000 floats
    const size_t QE = (size_t)N_NODES * 100;   // 10,000,000 floats
    float* P  = (float*)d_ws;
    float* q0 = P + PE;
    float* q1 = (ws_size >= (PE + 2 * QE) * sizeof(float)) ? (q0 + QE) : out;

    View vP{P, P + 100, 200};
    View vQ{q0, q1, 100};
    View vOut{out, out, 100};

    dim3 blk(256);
    const int mrows = (N_NODES + 63) / 64;
    const int sgrid = (int)(((size_t)N_EDGES * 200 + 255) / 256);

    // ---- S1 = X @ W1 -> P
    hipLaunchKernelGGL((gemm_k<false, false>), dim3((200 + 63) / 64, mrows), blk,
                       0, stream, feat_x, W1, nullptr, vP, N_NODES, 200, 256);
    // ---- A1 = segsum(w * S1[src]) -> Q   (h1 = relu(A1), applied later)
    hipMemsetAsync(q0, 0, QE * sizeof(float), stream);
    hipMemsetAsync(q1, 0, QE * sizeof(float), stream);
    hipLaunchKernelGGL((scatter_k<false>), dim3(sgrid), blk, 0, stream,
                       vP, vQ, src, dst, ew, N_EDGES);
    // ---- AGG2 = segsum(w * relu(A1)[src]) -> P   (input-side commute)
    hipMemsetAsync(P, 0, PE * sizeof(float), stream);
    hipLaunchKernelGGL((scatter_k<true>), dim3(sgrid), blk, 0, stream,
                       vQ, vP, src, dst, ew, N_EDGES);
    // ---- S3 = relu(AGG2 @ W2) @ W3 -> Q   (h2 never materialized)
    hipLaunchKernelGGL(fused_gemm_k, dim3(mrows), blk, 0, stream,
                       P, W2, W3, vQ, N_NODES);
    // ---- A3 = segsum(w * S3[src]) -> P   (h3 = relu(A3), applied in final)
    hipMemsetAsync(P, 0, PE * sizeof(float), stream);
    hipLaunchKernelGGL((scatter_k<false>), dim3(sgrid), blk, 0, stream,
                       vQ, vP, src, dst, ew, N_EDGES);
    // ---- out = relu(relu(A3) @ W_out + b_out)
    hipLaunchKernelGGL((gemm_k<true, true>), dim3((100 + 63) / 64, mrows), blk,
                       0, stream, P, W_out, b_out, vOut, N_NODES, 100, 200);
}

// Round 6
// 5374.528 us; speedup vs baseline: 1.4172x; 1.4172x over previous
//
#include <hip/hip_runtime.h>
#include <hip/hip_bf16.h>

#define N_NODES 100000
#define N_EDGES 1600000

using short8 = __attribute__((ext_vector_type(8))) short;
using f32x4  = __attribute__((ext_vector_type(4))) float;

// Split-panel matrix view: cols < split live in p0 (row stride s0), the rest
// in p1 (row stride s1). Lets a logical [M,200]/[M,300] matrix span two 40MB
// workspace regions and/or borrow d_out.
template <typename T>
struct V {
    T* p0; T* p1;
    int split;
    int s0; int s1;
};

template <typename T>
__device__ __forceinline__ T* vptr(const V<T> v, int r, int c) {
    return (c < v.split) ? v.p0 + (size_t)r * v.s0 + c
                         : v.p1 + (size_t)r * v.s1 + (c - v.split);
}

__device__ __forceinline__ unsigned short f2bf(float x) {
    union { float f; unsigned u; } un; un.f = x;
    unsigned r = un.u + 0x7fff + ((un.u >> 16) & 1);   // RNE
    return (unsigned short)(r >> 16);
}
__device__ __forceinline__ float bf2f(unsigned short b) {
    union { unsigned u; float f; } un; un.u = ((unsigned)b) << 16;
    return un.f;
}

// ---------------- MFMA GEMM: C[M,N] = op(A[M,K]) @ W[K,N] -----------------
// A: fp32 or bf16 via view; W: fp32 (converted to bf16 in staging).
// 128x64 tile, BK=32, 256 threads = 4 waves in 2x2, wave-tile 64x32
// (4 m-frags x 2 n-frags of 16x16), mfma_f32_16x16x32_bf16.
// LDS stride 40 elems (80B): 16B-aligned b128 reads, modest bank aliasing.
template <typename AT, typename OT, bool RELU_A, bool RELU_OUT, bool BIAS>
__global__ __launch_bounds__(256)
void mfma_gemm(V<AT> Av, const float* __restrict__ W,
               const float* __restrict__ bias, V<OT> Ov,
               int M, int N, int K) {
    constexpr int BM = 128, BN = 64, BK = 32, LS = 40;
    __shared__ __align__(16) unsigned short As[BM * LS];
    __shared__ __align__(16) unsigned short Bs[BN * LS];

    const int tid  = threadIdx.x;
    const int lane = tid & 63;
    const int wv   = tid >> 6;
    const int wr   = wv & 1;        // wave row (0..1) -> 64 rows each
    const int wc   = wv >> 1;       // wave col (0..1) -> 32 cols each
    const int row0 = blockIdx.y * BM;
    const int col0 = blockIdx.x * BN;
    const int fr   = lane & 15;     // fragment row/col index
    const int fg   = lane >> 4;     // k-group (0..3)

    f32x4 acc[4][2] = {};

    for (int k0 = 0; k0 < K; k0 += BK) {
        // A tile 128x32: elem e = tid + l*256 -> (r = e>>5, c = e&31).
        // Lanes cover 32 consecutive k -> coalesced global reads.
        #pragma unroll
        for (int l = 0; l < 16; ++l) {
            int r = (tid >> 5) + l * 8;
            int c = tid & 31;
            int gr = row0 + r, gk = k0 + c;
            unsigned short us = 0;
            if (gr < M && gk < K) {
                if constexpr (sizeof(AT) == 2) {
                    us = *reinterpret_cast<const unsigned short*>(vptr(Av, gr, gk));
                    if (RELU_A && (us & 0x8000u)) us = 0;
                } else {
                    float val = *vptr(Av, gr, gk);
                    if (RELU_A) val = fmaxf(val, 0.f);
                    us = f2bf(val);
                }
            }
            As[r * LS + c] = us;
        }
        // B tile 32x64 -> stored transposed Bs[col][k] for contiguous k reads.
        #pragma unroll
        for (int l = 0; l < 8; ++l) {
            int kr = (tid >> 6) + l * 4;
            int c  = tid & 63;
            int gk = k0 + kr, gc = col0 + c;
            float val = (gk < K && gc < N) ? W[(size_t)gk * N + gc] : 0.f;
            Bs[c * LS + kr] = f2bf(val);
        }
        __syncthreads();

        // b-frags first (2), then 4 m-frags x 2 MFMAs.
        short8 bfrag[2];
        #pragma unroll
        for (int ni = 0; ni < 2; ++ni)
            bfrag[ni] = *reinterpret_cast<const short8*>(
                &Bs[(wc * 32 + ni * 16 + fr) * LS + fg * 8]);
        #pragma unroll
        for (int mi = 0; mi < 4; ++mi) {
            short8 afrag = *reinterpret_cast<const short8*>(
                &As[(wr * 64 + mi * 16 + fr) * LS + fg * 8]);
            #pragma unroll
            for (int ni = 0; ni < 2; ++ni)
                acc[mi][ni] = __builtin_amdgcn_mfma_f32_16x16x32_bf16(
                    afrag, bfrag[ni], acc[mi][ni], 0, 0, 0);
        }
        __syncthreads();
    }

    // Epilogue: C[row = 4*fg + r (within frag), col = fr].
    #pragma unroll
    for (int mi = 0; mi < 4; ++mi) {
        #pragma unroll
        for (int ni = 0; ni < 2; ++ni) {
            int gc = col0 + wc * 32 + ni * 16 + fr;
            if (gc >= N) continue;
            float bv = BIAS ? bias[gc] : 0.f;
            #pragma unroll
            for (int r = 0; r < 4; ++r) {
                int gr = row0 + wr * 64 + mi * 16 + fg * 4 + r;
                if (gr >= M) continue;
                float v = acc[mi][ni][r];
                if (BIAS) v += bv;
                if (RELU_OUT) v = fmaxf(v, 0.f);
                if constexpr (sizeof(OT) == 2)
                    *reinterpret_cast<unsigned short*>(vptr(Ov, gr, gc)) = f2bf(v);
                else
                    *vptr(Ov, gr, gc) = v;
            }
        }
    }
}

// ---------------- Scatter: D[dst[e], f] += w[e] * op(S[src[e], f]) --------
template <typename ST, bool RELU_SRC>
__global__ __launch_bounds__(256)
void scatter_k(V<ST> Sv, V<float> Dv, const int* __restrict__ sidx,
               const int* __restrict__ didx, const float* __restrict__ w,
               int E) {
    int idx = blockIdx.x * 256 + threadIdx.x;
    int e = idx / 200;
    int f = idx - e * 200;
    if (e >= E) return;
    int s = sidx[e];
    int d = didx[e];
    float val;
    if constexpr (sizeof(ST) == 2)
        val = bf2f(*reinterpret_cast<const unsigned short*>(vptr(Sv, s, f)));
    else
        val = *vptr(Sv, s, f);
    if (RELU_SRC) val = fmaxf(val, 0.f);
    atomicAdd(vptr(Dv, d, f), w[e] * val);
}

extern "C" void kernel_launch(void* const* d_in, const int* in_sizes, int n_in,
                              void* d_out, int out_size, void* d_ws, size_t ws_size,
                              hipStream_t stream) {
    const float* feat_x = (const float*)d_in[0];
    const int*   src    = (const int*)d_in[1];
    const int*   dst    = (const int*)d_in[2];
    const float* ew     = (const float*)d_in[3];
    const float* W1     = (const float*)d_in[4];
    const float* W2     = (const float*)d_in[5];
    const float* W3     = (const float*)d_in[6];
    const float* W_out  = (const float*)d_in[7];
    const float* b_out  = (const float*)d_in[8];
    float* out = (float*)d_out;

    typedef __hip_bfloat16 bf;
    const int M = N_NODES, E = N_EDGES;

    // Three 40MB regions (10M floats each) = 120MB of d_ws (proven safe),
    // plus d_out (40MB) borrowed for intermediate panels until the final GEMM.
    const size_t QE = (size_t)M * 100;
    float* R0 = (float*)d_ws;
    float* R1 = R0 + QE;
    float* R2 = R0 + 2 * QE;

    V<float> vX   {(float*)feat_x, (float*)feat_x, 256, 256, 256};
    V<bf>    vS1  {(bf*)R2, (bf*)R2, 200, 200, 200};   // bf16 [M,200] in R2
    V<float> vA1  {R0, out, 100, 100, 100};            // fp32 [M,200] = R0|D
    V<float> vAGG2{R1, R2, 100, 100, 100};             // fp32 [M,200] = R1|R2
    V<bf>    vH2  {(bf*)R0, (bf*)out, 200, 200, 100};  // bf16 [M,300] = R0|D
    V<bf>    vS3  {(bf*)R1, (bf*)R1, 200, 200, 200};   // bf16 [M,200] in R1
    V<float> vA3  {R2, R0, 100, 100, 100};             // fp32 [M,200] = R2|R0
    V<float> vOut {out, out, 100, 100, 100};

    dim3 blk(256);
    const int mrows = (M + 127) / 128;                           // 782
    const int sgrid = (int)(((size_t)E * 200 + 255) / 256);      // 1.25M

    // 1) S1 = bf16(X @ W1)                      [K=256, N=200]
    hipLaunchKernelGGL((mfma_gemm<float, bf, false, false, false>),
                       dim3(4, mrows), blk, 0, stream,
                       vX, W1, (const float*)nullptr, vS1, M, 200, 256);
    // 2) A1 = segsum(w * S1[src])  (fp32, R0|D)
    hipMemsetAsync(R0, 0, QE * sizeof(float), stream);
    hipMemsetAsync(out, 0, QE * sizeof(float), stream);
    hipLaunchKernelGGL((scatter_k<bf, false>), dim3(sgrid), blk, 0, stream,
                       vS1, vA1, src, dst, ew, E);
    // 3) AGG2 = segsum(w * relu(A1)[src])  (fp32, R1|R2)
    hipMemsetAsync(R1, 0, QE * sizeof(float), stream);
    hipMemsetAsync(R2, 0, QE * sizeof(float), stream);
    hipLaunchKernelGGL((scatter_k<float, true>), dim3(sgrid), blk, 0, stream,
                       vA1, vAGG2, src, dst, ew, E);
    // 4) H2 = bf16(relu(AGG2 @ W2))             [K=200, N=300]
    hipLaunchKernelGGL((mfma_gemm<float, bf, false, true, false>),
                       dim3(5, mrows), blk, 0, stream,
                       vAGG2, W2, (const float*)nullptr, vH2, M, 300, 200);
    // 5) S3 = bf16(H2 @ W3)                     [K=300, N=200, A is bf16]
    hipLaunchKernelGGL((mfma_gemm<bf, bf, false, false, false>),
                       dim3(4, mrows), blk, 0, stream,
                       vH2, W3, (const float*)nullptr, vS3, M, 200, 300);
    // 6) A3 = segsum(w * S3[src])  (fp32, R2|R0)
    hipMemsetAsync(R2, 0, QE * sizeof(float), stream);
    hipMemsetAsync(R0, 0, QE * sizeof(float), stream);
    hipLaunchKernelGGL((scatter_k<bf, false>), dim3(sgrid), blk, 0, stream,
                       vS3, vA3, src, dst, ew, E);
    // 7) out = relu(relu(A3) @ W_out + b_out)   [K=200, N=100]
    hipLaunchKernelGGL((mfma_gemm<float, float, true, true, true>),
                       dim3(2, mrows), blk, 0, stream,
                       vA3, W_out, b_out, vOut, M, 100, 200);
}

// Round 8
// 1705.980 us; speedup vs baseline: 4.4647x; 3.1504x over previous
//
#include <hip/hip_runtime.h>
#include <hip/hip_bf16.h>

#define N_NODES 100000
#define N_EDGES 1600000

using short8 = __attribute__((ext_vector_type(8))) short;
using f32x4  = __attribute__((ext_vector_type(4))) float;

__device__ __forceinline__ unsigned short f2bf(float x) {
    union { float f; unsigned u; } un; un.f = x;
    unsigned r = un.u + 0x7fff + ((un.u >> 16) & 1);   // RNE
    return (unsigned short)(r >> 16);
}
__device__ __forceinline__ float bf2f(unsigned short b) {
    union { unsigned u; float f; } un; un.u = ((unsigned)b) << 16;
    return un.f;
}

// ---------------- CSR build ------------------------------------------------
__global__ __launch_bounds__(256)
void zero_k(int* __restrict__ p, int n) {
    int i = blockIdx.x * 256 + threadIdx.x;
    if (i < n) p[i] = 0;
}

__global__ __launch_bounds__(256)
void hist_k(const int* __restrict__ dst, int* __restrict__ rp, int E) {
    int e = blockIdx.x * 256 + threadIdx.x;
    if (e < E) atomicAdd(&rp[dst[e] + 1], 1);
}

// Single-block inclusive scan, in place (n up to ~200K).
__global__ __launch_bounds__(1024)
void scan_k(int* __restrict__ a, int n) {
    __shared__ int buf[2][1024];
    __shared__ int carry_s;
    const int tid = threadIdx.x;
    if (tid == 0) carry_s = 0;
    __syncthreads();
    for (int base = 0; base < n; base += 1024) {
        int i = base + tid;
        int v = (i < n) ? a[i] : 0;
        int cur = 0;
        buf[0][tid] = v;
        __syncthreads();
        #pragma unroll
        for (int off = 1; off < 1024; off <<= 1) {
            int nv = buf[cur][tid] + ((tid >= off) ? buf[cur][tid - off] : 0);
            buf[cur ^ 1][tid] = nv;
            cur ^= 1;
            __syncthreads();
        }
        int incl = buf[cur][tid];
        if (i < n) a[i] = incl + carry_s;
        int total = buf[cur][1023];
        __syncthreads();
        if (tid == 0) carry_s += total;
        __syncthreads();
    }
}

__global__ __launch_bounds__(256)
void fill_k(const int* __restrict__ src, const int* __restrict__ dst,
            const float* __restrict__ w, const int* __restrict__ rp,
            int* __restrict__ fill, int* __restrict__ psrc,
            float* __restrict__ pw, int E) {
    int e = blockIdx.x * 256 + threadIdx.x;
    if (e >= E) return;
    int d = dst[e];
    int pos = rp[d] + atomicAdd(&fill[d], 1);
    psrc[pos] = src[e];
    pw[pos]   = w[e];
}

// ---------------- CSR aggregation -----------------------------------------
// out[i,:] = (relu?) sum_{e in row i} pw[e] * S[psrc[e], :]   (F = 200 bf16)
// 25 threads/node x bf16x8 chunk; 250 threads/block = 10 nodes/block.
// fp32 accumulation in registers; each output row written exactly once.
template <bool RELU_OUT>
__global__ __launch_bounds__(256)
void agg_k(const unsigned short* __restrict__ S, const int* __restrict__ rp,
           const int* __restrict__ psrc, const float* __restrict__ pw,
           unsigned short* __restrict__ out, int M) {
    const int tid = threadIdx.x;
    const int g = tid / 25;          // node slot 0..9
    const int s = tid - g * 25;      // 16B chunk 0..24
    const int node = blockIdx.x * 10 + g;
    if (node >= M) return;
    const int r0 = rp[node], r1 = rp[node + 1];
    float acc[8] = {};
    for (int e = r0; e < r1; ++e) {
        const int sn = psrc[e];
        const float w = pw[e];
        short8 v = *reinterpret_cast<const short8*>(&S[(size_t)sn * 200 + s * 8]);
        #pragma unroll
        for (int j = 0; j < 8; ++j)
            acc[j] += w * bf2f((unsigned short)v[j]);
    }
    short8 o;
    #pragma unroll
    for (int j = 0; j < 8; ++j) {
        float v = RELU_OUT ? fmaxf(acc[j], 0.f) : acc[j];
        o[j] = (short)f2bf(v);
    }
    *reinterpret_cast<short8*>(&out[(size_t)node * 200 + s * 8]) = o;
}

// ---------------- MFMA GEMM: C[M,N] = A[M,K] @ W[K,N] (+bias,+relu) -------
// A: fp32 or bf16 (unsigned short); W fp32 converted in staging.
// 128x64 tile, BK=32, 4 waves 2x2, wave-tile 64x32, mfma_f32_16x16x32_bf16.
template <typename AT, typename OT, bool RELU_OUT, bool BIAS>
__global__ __launch_bounds__(256)
void mfma_gemm(const AT* __restrict__ A, const float* __restrict__ W,
               const float* __restrict__ bias, OT* __restrict__ C,
               int M, int N, int K) {
    constexpr int BM = 128, BN = 64, BK = 32, LS = 40;
    __shared__ __align__(16) unsigned short As[BM * LS];
    __shared__ __align__(16) unsigned short Bs[BN * LS];

    const int tid  = threadIdx.x;
    const int lane = tid & 63;
    const int wv   = tid >> 6;
    const int wr   = wv & 1;
    const int wc   = wv >> 1;
    const int row0 = blockIdx.y * BM;
    const int col0 = blockIdx.x * BN;
    const int fr   = lane & 15;
    const int fg   = lane >> 4;

    f32x4 acc[4][2] = {};

    for (int k0 = 0; k0 < K; k0 += BK) {
        #pragma unroll
        for (int l = 0; l < 16; ++l) {
            int r = (tid >> 5) + l * 8;
            int c = tid & 31;
            int gr = row0 + r, gk = k0 + c;
            unsigned short us = 0;
            if (gr < M && gk < K) {
                if constexpr (sizeof(AT) == 2)
                    us = *reinterpret_cast<const unsigned short*>(&A[(size_t)gr * K + gk]);
                else
                    us = f2bf(A[(size_t)gr * K + gk]);
            }
            As[r * LS + c] = us;
        }
        #pragma unroll
        for (int l = 0; l < 8; ++l) {
            int kr = (tid >> 6) + l * 4;
            int c  = tid & 63;
            int gk = k0 + kr, gc = col0 + c;
            float val = (gk < K && gc < N) ? W[(size_t)gk * N + gc] : 0.f;
            Bs[c * LS + kr] = f2bf(val);
        }
        __syncthreads();

        short8 bfrag[2];
        #pragma unroll
        for (int ni = 0; ni < 2; ++ni)
            bfrag[ni] = *reinterpret_cast<const short8*>(
                &Bs[(wc * 32 + ni * 16 + fr) * LS + fg * 8]);
        #pragma unroll
        for (int mi = 0; mi < 4; ++mi) {
            short8 afrag = *reinterpret_cast<const short8*>(
                &As[(wr * 64 + mi * 16 + fr) * LS + fg * 8]);
            #pragma unroll
            for (int ni = 0; ni < 2; ++ni)
                acc[mi][ni] = __builtin_amdgcn_mfma_f32_16x16x32_bf16(
                    afrag, bfrag[ni], acc[mi][ni], 0, 0, 0);
        }
        __syncthreads();
    }

    #pragma unroll
    for (int mi = 0; mi < 4; ++mi) {
        #pragma unroll
        for (int ni = 0; ni < 2; ++ni) {
            int gc = col0 + wc * 32 + ni * 16 + fr;
            if (gc >= N) continue;
            float bv = BIAS ? bias[gc] : 0.f;
            #pragma unroll
            for (int r = 0; r < 4; ++r) {
                int gr = row0 + wr * 64 + mi * 16 + fg * 4 + r;
                if (gr >= M) continue;
                float v = acc[mi][ni][r];
                if (BIAS) v += bv;
                if (RELU_OUT) v = fmaxf(v, 0.f);
                if constexpr (sizeof(OT) == 2)
                    *reinterpret_cast<unsigned short*>(&C[(size_t)gr * N + gc]) = f2bf(v);
                else
                    C[(size_t)gr * N + gc] = v;
            }
        }
    }
}

extern "C" void kernel_launch(void* const* d_in, const int* in_sizes, int n_in,
                              void* d_out, int out_size, void* d_ws, size_t ws_size,
                              hipStream_t stream) {
    const float* feat_x = (const float*)d_in[0];
    const int*   src    = (const int*)d_in[1];
    const int*   dst    = (const int*)d_in[2];
    const float* ew     = (const float*)d_in[3];
    const float* W1     = (const float*)d_in[4];
    const float* W2     = (const float*)d_in[5];
    const float* W3     = (const float*)d_in[6];
    const float* W_out  = (const float*)d_in[7];
    const float* b_out  = (const float*)d_in[8];
    float* out = (float*)d_out;

    const int M = N_NODES, E = N_EDGES;
    char* ws = (char*)d_ws;

    // ---- workspace layout (116 MB total; 120 MB proven safe) ----
    // [0, 16MB): CSR block
    int*   rp   = (int*)(ws);                    // 100001 ints
    int*   fill = (int*)(ws + 402432);           // 100000 ints
    int*   psrc = (int*)(ws + 802816);           // 1.6M ints
    float* pw   = (float*)(ws + 7202816);        // 1.6M floats (ends ~13.6MB)
    // [16MB, 56MB): slotP (40MB)   [56MB, 116MB): slotQ (60MB)
    unsigned short* slotP = (unsigned short*)(ws + (size_t)16 * 1024 * 1024);
    unsigned short* slotQ = (unsigned short*)(ws + (size_t)56 * 1024 * 1024);

    unsigned short* S1   = slotP;   // bf16 [M,200]
    unsigned short* h1   = slotQ;   // bf16 [M,200] (relu'd aggregate)
    unsigned short* AGG2 = slotP;   // bf16 [M,200]
    unsigned short* H2   = slotQ;   // bf16 [M,300]
    unsigned short* S3   = slotP;   // bf16 [M,200]
    unsigned short* h3   = slotQ;   // bf16 [M,200] (relu'd aggregate)

    dim3 blk(256);
    const int mrows = (M + 127) / 128;     // 782
    const int egrid = (E + 255) / 256;
    const int agrid = (M + 9) / 10;

    // ---- CSR build (by dst), reused by all 3 aggregations ----
    hipLaunchKernelGGL(zero_k, dim3((200704 + 255) / 256), blk, 0, stream,
                       (int*)ws, 200704);          // rp + fill region
    hipLaunchKernelGGL(hist_k, dim3(egrid), blk, 0, stream, dst, rp, E);
    hipLaunchKernelGGL(scan_k, dim3(1), dim3(1024), 0, stream, rp, M + 1);
    hipLaunchKernelGGL(fill_k, dim3(egrid), blk, 0, stream,
                       src, dst, ew, rp, fill, psrc, pw, E);

    // 1) S1 = bf16(X @ W1)                        [K=256, N=200]
    hipLaunchKernelGGL((mfma_gemm<float, unsigned short, false, false>),
                       dim3(4, mrows), blk, 0, stream,
                       feat_x, W1, (const float*)nullptr, S1, M, 200, 256);
    // 2) h1 = relu(segsum(w * S1[src]))
    hipLaunchKernelGGL((agg_k<true>), dim3(agrid), dim3(250), 0, stream,
                       S1, rp, psrc, pw, h1, M);
    // 3) AGG2 = segsum(w * h1[src])
    hipLaunchKernelGGL((agg_k<false>), dim3(agrid), dim3(250), 0, stream,
                       h1, rp, psrc, pw, AGG2, M);
    // 4) H2 = bf16(relu(AGG2 @ W2))               [K=200, N=300]
    hipLaunchKernelGGL((mfma_gemm<unsigned short, unsigned short, true, false>),
                       dim3(5, mrows), blk, 0, stream,
                       AGG2, W2, (const float*)nullptr, H2, M, 300, 200);
    // 5) S3 = bf16(H2 @ W3)                       [K=300, N=200]
    hipLaunchKernelGGL((mfma_gemm<unsigned short, unsigned short, false, false>),
                       dim3(4, mrows), blk, 0, stream,
                       H2, W3, (const float*)nullptr, S3, M, 200, 300);
    // 6) h3 = relu(segsum(w * S3[src]))
    hipLaunchKernelGGL((agg_k<true>), dim3(agrid), dim3(250), 0, stream,
                       S3, rp, psrc, pw, h3, M);
    // 7) out = relu(h3 @ W_out + b_out)           [K=200, N=100]
    hipLaunchKernelGGL((mfma_gemm<unsigned short, float, true, true>),
                       dim3(2, mrows), blk, 0, stream,
                       h3, W_out, b_out, out, M, 100, 200);
}

// Round 9
// 1113.094 us; speedup vs baseline: 6.8428x; 1.5326x over previous
//
#include <hip/hip_runtime.h>
#include <hip/hip_bf16.h>

#define N_NODES 100000
#define N_EDGES 1600000

using short8 = __attribute__((ext_vector_type(8))) short;
using f32x4  = __attribute__((ext_vector_type(4))) float;

__device__ __forceinline__ unsigned short f2bf(float x) {
    union { float f; unsigned u; } un; un.f = x;
    unsigned r = un.u + 0x7fff + ((un.u >> 16) & 1);   // RNE
    return (unsigned short)(r >> 16);
}
__device__ __forceinline__ float bf2f(unsigned short b) {
    union { unsigned u; float f; } un; un.u = ((unsigned)b) << 16;
    return un.f;
}

// ---------------- input conversions ---------------------------------------
// X fp32 -> bf16, 8 elems/thread (n must be a multiple of 8).
__global__ __launch_bounds__(256)
void convx_k(const float* __restrict__ X, unsigned short* __restrict__ Xb,
             long n) {
    long i = ((long)blockIdx.x * 256 + threadIdx.x) * 8;
    if (i >= n) return;
    f32x4 a = *reinterpret_cast<const f32x4*>(X + i);
    f32x4 b = *reinterpret_cast<const f32x4*>(X + i + 4);
    short8 o;
    o[0] = (short)f2bf(a[0]); o[1] = (short)f2bf(a[1]);
    o[2] = (short)f2bf(a[2]); o[3] = (short)f2bf(a[3]);
    o[4] = (short)f2bf(b[0]); o[5] = (short)f2bf(b[1]);
    o[6] = (short)f2bf(b[2]); o[7] = (short)f2bf(b[3]);
    *reinterpret_cast<short8*>(Xb + i) = o;
}

// W [K][N] fp32 -> WT [Np][Kp] bf16 (zero-padded outside K x N).
__global__ __launch_bounds__(256)
void convwt_k(const float* __restrict__ W, unsigned short* __restrict__ WT,
              int K, int N, int Kp, int Np) {
    int idx = blockIdx.x * 256 + threadIdx.x;
    if (idx >= Np * Kp) return;
    int nr = idx / Kp, k = idx - nr * Kp;
    WT[idx] = (nr < N && k < K) ? f2bf(W[(size_t)k * N + nr]) : (unsigned short)0;
}

// ---------------- CSR build ------------------------------------------------
__global__ __launch_bounds__(256)
void zero_k(int* __restrict__ p, int n) {
    int i = blockIdx.x * 256 + threadIdx.x;
    if (i < n) p[i] = 0;
}

__global__ __launch_bounds__(256)
void hist_k(const int* __restrict__ dst, int* __restrict__ rp, int E) {
    int e = blockIdx.x * 256 + threadIdx.x;
    if (e < E) atomicAdd(&rp[dst[e] + 1], 1);
}

// Single-block inclusive scan, in place.
__global__ __launch_bounds__(1024)
void scan_k(int* __restrict__ a, int n) {
    __shared__ int buf[2][1024];
    __shared__ int carry_s;
    const int tid = threadIdx.x;
    if (tid == 0) carry_s = 0;
    __syncthreads();
    for (int base = 0; base < n; base += 1024) {
        int i = base + tid;
        int v = (i < n) ? a[i] : 0;
        int cur = 0;
        buf[0][tid] = v;
        __syncthreads();
        #pragma unroll
        for (int off = 1; off < 1024; off <<= 1) {
            int nv = buf[cur][tid] + ((tid >= off) ? buf[cur][tid - off] : 0);
            buf[cur ^ 1][tid] = nv;
            cur ^= 1;
            __syncthreads();
        }
        int incl = buf[cur][tid];
        if (i < n) a[i] = incl + carry_s;
        int total = buf[cur][1023];
        __syncthreads();
        if (tid == 0) carry_s += total;
        __syncthreads();
    }
}

__global__ __launch_bounds__(256)
void fill_k(const int* __restrict__ src, const int* __restrict__ dst,
            const float* __restrict__ w, const int* __restrict__ rp,
            int* __restrict__ fill, int* __restrict__ psrc,
            float* __restrict__ pw, int E) {
    int e = blockIdx.x * 256 + threadIdx.x;
    if (e >= E) return;
    int d = dst[e];
    int pos = rp[d] + atomicAdd(&fill[d], 1);
    psrc[pos] = src[e];
    pw[pos]   = w[e];
}

// ---------------- CSR aggregation (F = 200 bf16) --------------------------
// 25 threads/node x bf16x8 chunk; 250 threads/block = 10 nodes/block.
template <bool RELU_OUT>
__global__ __launch_bounds__(256)
void agg_k(const unsigned short* __restrict__ S, const int* __restrict__ rp,
           const int* __restrict__ psrc, const float* __restrict__ pw,
           unsigned short* __restrict__ out, int M) {
    const int tid = threadIdx.x;
    const int g = tid / 25;
    const int s = tid - g * 25;
    const int node = blockIdx.x * 10 + g;
    if (node >= M) return;
    const int r0 = rp[node], r1 = rp[node + 1];
    float acc[8] = {};
    for (int e = r0; e < r1; ++e) {
        const int sn = psrc[e];
        const float w = pw[e];
        short8 v = *reinterpret_cast<const short8*>(&S[(size_t)sn * 200 + s * 8]);
        #pragma unroll
        for (int j = 0; j < 8; ++j)
            acc[j] += w * bf2f((unsigned short)v[j]);
    }
    short8 o;
    #pragma unroll
    for (int j = 0; j < 8; ++j) {
        float v = RELU_OUT ? fmaxf(acc[j], 0.f) : acc[j];
        o[j] = (short)f2bf(v);
    }
    *reinterpret_cast<short8*>(&out[(size_t)node * 200 + s * 8]) = o;
}

// ---------------- MFMA GEMM: C[M,N] = A[M,K]bf16 @ BT[N,K]bf16^T ----------
// Both operands row-major [*][K]; staging = short8 global loads + b128 LDS
// writes. 128x64 tile, BK=32, 4 waves 2x2, mfma_f32_16x16x32_bf16.
// K and all row strides must be multiples of 8 (16B-aligned rows).
template <typename OT, bool RELU_OUT, bool BIAS>
__global__ __launch_bounds__(256)
void mfma_gemm(const unsigned short* __restrict__ A,
               const unsigned short* __restrict__ BT,
               const float* __restrict__ bias, OT* __restrict__ C,
               int M, int N, int K) {
    constexpr int BM = 128, BN = 64, BK = 32, LS = 40;
    __shared__ __align__(16) unsigned short As[BM * LS];
    __shared__ __align__(16) unsigned short Bs[BN * LS];

    const int tid  = threadIdx.x;
    const int lane = tid & 63;
    const int wv   = tid >> 6;
    const int wr   = wv & 1;
    const int wc   = wv >> 1;
    const int row0 = blockIdx.y * BM;
    const int col0 = blockIdx.x * BN;
    const int fr   = lane & 15;
    const int fg   = lane >> 4;

    f32x4 acc[4][2] = {};
    const short8 zed = {};

    for (int k0 = 0; k0 < K; k0 += BK) {
        // A tile 128x32 = 512 16B-chunks, 2/thread.
        #pragma unroll
        for (int l = 0; l < 2; ++l) {
            int c = tid + l * 256;
            int r = c >> 2;
            int off = (c & 3) * 8;
            int gr = row0 + r, gk = k0 + off;
            short8 v = (gr < M && gk < K)
                ? *reinterpret_cast<const short8*>(&A[(size_t)gr * K + gk]) : zed;
            *reinterpret_cast<short8*>(&As[r * LS + off]) = v;
        }
        // B tile 64x32 = 256 16B-chunks, 1/thread.
        {
            int r = tid >> 2;
            int off = (tid & 3) * 8;
            int gn = col0 + r, gk = k0 + off;
            short8 v = (gn < N && gk < K)
                ? *reinterpret_cast<const short8*>(&BT[(size_t)gn * K + gk]) : zed;
            *reinterpret_cast<short8*>(&Bs[r * LS + off]) = v;
        }
        __syncthreads();

        short8 bfrag[2];
        #pragma unroll
        for (int ni = 0; ni < 2; ++ni)
            bfrag[ni] = *reinterpret_cast<const short8*>(
                &Bs[(wc * 32 + ni * 16 + fr) * LS + fg * 8]);
        #pragma unroll
        for (int mi = 0; mi < 4; ++mi) {
            short8 afrag = *reinterpret_cast<const short8*>(
                &As[(wr * 64 + mi * 16 + fr) * LS + fg * 8]);
            #pragma unroll
            for (int ni = 0; ni < 2; ++ni)
                acc[mi][ni] = __builtin_amdgcn_mfma_f32_16x16x32_bf16(
                    afrag, bfrag[ni], acc[mi][ni], 0, 0, 0);
        }
        __syncthreads();
    }

    #pragma unroll
    for (int mi = 0; mi < 4; ++mi) {
        #pragma unroll
        for (int ni = 0; ni < 2; ++ni) {
            int gc = col0 + wc * 32 + ni * 16 + fr;
            if (gc >= N) continue;
            float bv = BIAS ? bias[gc] : 0.f;
            #pragma unroll
            for (int r = 0; r < 4; ++r) {
                int gr = row0 + wr * 64 + mi * 16 + fg * 4 + r;
                if (gr >= M) continue;
                float v = acc[mi][ni][r];
                if (BIAS) v += bv;
                if (RELU_OUT) v = fmaxf(v, 0.f);
                if constexpr (sizeof(OT) == 2)
                    *reinterpret_cast<unsigned short*>(&C[(size_t)gr * N + gc]) = f2bf(v);
                else
                    C[(size_t)gr * N + gc] = v;
            }
        }
    }
}

extern "C" void kernel_launch(void* const* d_in, const int* in_sizes, int n_in,
                              void* d_out, int out_size, void* d_ws, size_t ws_size,
                              hipStream_t stream) {
    const float* feat_x = (const float*)d_in[0];
    const int*   src    = (const int*)d_in[1];
    const int*   dst    = (const int*)d_in[2];
    const float* ew     = (const float*)d_in[3];
    const float* W1     = (const float*)d_in[4];
    const float* W2     = (const float*)d_in[5];
    const float* W3     = (const float*)d_in[6];
    const float* W_out  = (const float*)d_in[7];
    const float* b_out  = (const float*)d_in[8];
    float* out = (float*)d_out;

    const int M = N_NODES, E = N_EDGES;
    char* ws = (char*)d_ws;

    // ---- workspace layout (~114 MB; 120 MB proven safe) ----
    int*   rp   = (int*)(ws);                         // 100001 ints
    int*   fill = (int*)(ws + 402432);                // 100000 ints
    int*   psrc = (int*)(ws + 802816);                // 1.6M ints
    float* pw   = (float*)(ws + 7202816);             // 1.6M floats
    unsigned short* w1t = (unsigned short*)(ws + 13602816);  // [200][256]
    unsigned short* w2t = (unsigned short*)(ws + 13705216);  // [304][200]
    unsigned short* w3t = (unsigned short*)(ws + 13826816);  // [200][304]
    unsigned short* wot = (unsigned short*)(ws + 13948416);  // [100][200]
    unsigned short* slotP = (unsigned short*)(ws + 16777216);  // 40.0 MB
    unsigned short* slotQ = (unsigned short*)(ws + 58720256);  // 60.8 MB

    unsigned short* Xbf  = slotQ;   // bf16 [M,256] (dead after GEMM1)
    unsigned short* S1   = slotP;   // bf16 [M,200]
    unsigned short* h1   = slotQ;   // bf16 [M,200]
    unsigned short* AGG2 = slotP;   // bf16 [M,200]
    unsigned short* H2   = slotQ;   // bf16 [M,304] (pad cols zero)
    unsigned short* S3   = slotP;   // bf16 [M,200]
    unsigned short* h3   = slotQ;   // bf16 [M,200]

    dim3 blk(256);
    const int mrows = (M + 127) / 128;     // 782
    const int egrid = (E + 255) / 256;
    const int agrid = (M + 9) / 10;

    // ---- conversions (independent of CSR) ----
    hipLaunchKernelGGL(convx_k, dim3((int)(((long)M * 256 / 8 + 255) / 256)), blk,
                       0, stream, feat_x, Xbf, (long)M * 256);
    hipLaunchKernelGGL(convwt_k, dim3((200 * 256 + 255) / 256), blk, 0, stream,
                       W1, w1t, 256, 200, 256, 200);
    hipLaunchKernelGGL(convwt_k, dim3((304 * 200 + 255) / 256), blk, 0, stream,
                       W2, w2t, 200, 300, 200, 304);
    hipLaunchKernelGGL(convwt_k, dim3((200 * 304 + 255) / 256), blk, 0, stream,
                       W3, w3t, 300, 200, 304, 200);
    hipLaunchKernelGGL(convwt_k, dim3((100 * 200 + 255) / 256), blk, 0, stream,
                       W_out, wot, 200, 100, 200, 100);

    // ---- CSR build (by dst), reused by all 3 aggregations ----
    hipLaunchKernelGGL(zero_k, dim3((200704 + 255) / 256), blk, 0, stream,
                       (int*)ws, 200704);
    hipLaunchKernelGGL(hist_k, dim3(egrid), blk, 0, stream, dst, rp, E);
    hipLaunchKernelGGL(scan_k, dim3(1), dim3(1024), 0, stream, rp, M + 1);
    hipLaunchKernelGGL(fill_k, dim3(egrid), blk, 0, stream,
                       src, dst, ew, rp, fill, psrc, pw, E);

    // 1) S1 = bf16(X @ W1)                        [K=256, N=200]
    hipLaunchKernelGGL((mfma_gemm<unsigned short, false, false>),
                       dim3(4, mrows), blk, 0, stream,
                       Xbf, w1t, (const float*)nullptr, S1, M, 200, 256);
    // 2) h1 = relu(segsum(w * S1[src]))
    hipLaunchKernelGGL((agg_k<true>), dim3(agrid), dim3(250), 0, stream,
                       S1, rp, psrc, pw, h1, M);
    // 3) AGG2 = segsum(w * h1[src])
    hipLaunchKernelGGL((agg_k<false>), dim3(agrid), dim3(250), 0, stream,
                       h1, rp, psrc, pw, AGG2, M);
    // 4) H2 = bf16(relu(AGG2 @ W2)) padded        [K=200, N=304]
    hipLaunchKernelGGL((mfma_gemm<unsigned short, true, false>),
                       dim3(5, mrows), blk, 0, stream,
                       AGG2, w2t, (const float*)nullptr, H2, M, 304, 200);
    // 5) S3 = bf16(H2 @ W3)                       [K=304, N=200]
    hipLaunchKernelGGL((mfma_gemm<unsigned short, false, false>),
                       dim3(4, mrows), blk, 0, stream,
                       H2, w3t, (const float*)nullptr, S3, M, 200, 304);
    // 6) h3 = relu(segsum(w * S3[src]))
    hipLaunchKernelGGL((agg_k<true>), dim3(agrid), dim3(250), 0, stream,
                       S3, rp, psrc, pw, h3, M);
    // 7) out = relu(h3 @ W_out + b_out)           [K=200, N=100]
    hipLaunchKernelGGL((mfma_gemm<float, true, true>),
                       dim3(2, mrows), blk, 0, stream,
                       h3, wot, b_out, out, M, 100, 200);
}